// Round 1
// baseline (3668.852 us; speedup 1.0000x reference)
//
#include <hip/hip_runtime.h>
#include <hip/hip_bf16.h>

// 2-layer GAT, H=2 heads, D=64 per head, F_IN=128, all fp32.
// Pipeline: CSR build (by dst) -> [GEMM -> el/er -> aggregate] x2.

#define NEG_SLOPE 0.2f
#define SCAN_CHUNK 1024

// ---------------- CSR build ----------------

__global__ void k_hist(const int* __restrict__ dst, int E, int* __restrict__ deg) {
    int e = blockIdx.x * 256 + threadIdx.x;
    if (e < E) atomicAdd(&deg[dst[e]], 1);
}

__global__ void k_block_sum(const int* __restrict__ deg, int n, int* __restrict__ bsum) {
    __shared__ int sdata[256];
    int base = blockIdx.x * SCAN_CHUNK;
    int t = threadIdx.x;
    int s = 0;
    for (int j = t; j < SCAN_CHUNK; j += 256) {
        int idx = base + j;
        s += (idx < n) ? deg[idx] : 0;
    }
    sdata[t] = s;
    __syncthreads();
    for (int off = 128; off > 0; off >>= 1) {
        if (t < off) sdata[t] += sdata[t + off];
        __syncthreads();
    }
    if (t == 0) bsum[blockIdx.x] = sdata[0];
}

__global__ void k_scan_bsum(int* __restrict__ bsum, int nb) {
    // single block of 256 threads; exclusive scan of bsum[0..nb)
    __shared__ int sd[256];
    int t = threadIdx.x;
    sd[t] = (t < nb) ? bsum[t] : 0;
    __syncthreads();
    for (int off = 1; off < 256; off <<= 1) {
        int v = (t >= off) ? sd[t - off] : 0;
        __syncthreads();
        sd[t] += v;
        __syncthreads();
    }
    if (t < nb) bsum[t] = (t == 0) ? 0 : sd[t - 1];
}

__global__ void k_scan_final(const int* __restrict__ deg, int n,
                             const int* __restrict__ bsum,
                             int* __restrict__ rowStart, int* __restrict__ cursor, int E) {
    __shared__ int sd[256];
    int base = blockIdx.x * SCAN_CHUNK;
    int t = threadIdx.x;
    int idx0 = base + t * 4;
    int v[4];
    int s = 0;
    for (int j = 0; j < 4; j++) {
        int idx = idx0 + j;
        v[j] = (idx < n) ? deg[idx] : 0;
        s += v[j];
    }
    sd[t] = s;
    __syncthreads();
    for (int off = 1; off < 256; off <<= 1) {
        int x = (t >= off) ? sd[t - off] : 0;
        __syncthreads();
        sd[t] += x;
        __syncthreads();
    }
    int running = bsum[blockIdx.x] + ((t == 0) ? 0 : sd[t - 1]);
    for (int j = 0; j < 4; j++) {
        int idx = idx0 + j;
        if (idx < n) {
            rowStart[idx] = running;
            cursor[idx] = running;
        }
        running += v[j];
    }
    if (blockIdx.x == 0 && t == 0) rowStart[n] = E;
}

__global__ void k_scatter(const int* __restrict__ src, const int* __restrict__ dst, int E,
                          int* __restrict__ cursor, int* __restrict__ csr) {
    int e = blockIdx.x * 256 + threadIdx.x;
    if (e < E) {
        int d = dst[e];
        int p = atomicAdd(&cursor[d], 1);
        csr[p] = src[e];
    }
}

// ---------------- GEMM: C[M][128] = A[M][128] @ W[128][128] (fp32) ----------------

#define GEMM_ROWS 64
__global__ __launch_bounds__(256) void k_gemm128(const float* __restrict__ A,
                                                 const float* __restrict__ W,
                                                 float* __restrict__ C, int M) {
    __shared__ float xs[GEMM_ROWS][128];   // 32 KB
    __shared__ float ws[32][128];          // 16 KB
    int row0 = blockIdx.x * GEMM_ROWS;
    int t = threadIdx.x;

    // stage x tile: 64 rows x 128 = 2048 float4, 8 per thread, coalesced
    for (int j = 0; j < 8; j++) {
        int f4 = t + j * 256;
        int r = f4 >> 5;       // 32 float4 per row
        int c4 = f4 & 31;
        float4 v = make_float4(0.f, 0.f, 0.f, 0.f);
        int gr = row0 + r;
        if (gr < M) v = ((const float4*)(A + (size_t)gr * 128))[c4];
        ((float4*)&xs[r][0])[c4] = v;
    }

    int tc = t & 31;   // col group (4 cols)
    int tr = t >> 5;   // row group (8 rows)
    float4 acc[8];
    for (int i = 0; i < 8; i++) acc[i] = make_float4(0.f, 0.f, 0.f, 0.f);

    for (int kt = 0; kt < 4; kt++) {
        __syncthreads();
        // stage W rows [kt*32, kt*32+32): 1024 float4, 4 per thread
        for (int j = 0; j < 4; j++) {
            int f4 = t + j * 256;
            int r = f4 >> 5;
            int c4 = f4 & 31;
            ((float4*)&ws[r][0])[c4] = ((const float4*)(W + (size_t)(kt * 32 + r) * 128))[c4];
        }
        __syncthreads();
        for (int k = 0; k < 32; k++) {
            float4 w4 = ((float4*)&ws[k][0])[tc];
            #pragma unroll
            for (int i = 0; i < 8; i++) {
                float xv = xs[tr * 8 + i][kt * 32 + k];
                acc[i].x += xv * w4.x;
                acc[i].y += xv * w4.y;
                acc[i].z += xv * w4.z;
                acc[i].w += xv * w4.w;
            }
        }
    }
    for (int i = 0; i < 8; i++) {
        int gr = row0 + tr * 8 + i;
        if (gr < M) ((float4*)(C + (size_t)gr * 128))[tc] = acc[i];
    }
}

// ---------------- el/er: [N,2] attention projections ----------------

__global__ void k_elr(const float* __restrict__ h, const float* __restrict__ al,
                      const float* __restrict__ ar, float* __restrict__ el,
                      float* __restrict__ er, int N) {
    int t = blockIdx.x * 256 + threadIdx.x;
    int n = t >> 1;
    int hd = t & 1;
    if (n >= N) return;
    const float* hp = h + (size_t)n * 128 + hd * 64;
    const float* alp = al + hd * 64;
    const float* arp = ar + hd * 64;
    float sl = 0.f, sr = 0.f;
    for (int j = 0; j < 16; j++) {
        float4 hv = ((const float4*)hp)[j];
        float4 av = ((const float4*)alp)[j];
        float4 rv = ((const float4*)arp)[j];
        sl += hv.x * av.x + hv.y * av.y + hv.z * av.z + hv.w * av.w;
        sr += hv.x * rv.x + hv.y * rv.y + hv.z * rv.z + hv.w * rv.w;
    }
    el[n * 2 + hd] = sl;
    er[n * 2 + hd] = sr;
}

// ---------------- aggregate: per-node edge softmax + weighted sum ----------------
// One wave (64 lanes) per node. Lane l owns output dims 2l, 2l+1
// (l<32 -> head0 dims 0..63, l>=32 -> head1 dims 64..127).

template <bool RELU>
__global__ __launch_bounds__(256) void k_agg(const float* __restrict__ h,
                                             const float* __restrict__ el,
                                             const float* __restrict__ er,
                                             const int* __restrict__ rowStart,
                                             const int* __restrict__ csr,
                                             const float* __restrict__ bias,
                                             float* __restrict__ out, int N) {
    int wave = threadIdx.x >> 6;
    int lane = threadIdx.x & 63;
    int n = blockIdx.x * 4 + wave;
    if (n >= N) return;

    int rs = rowStart[n];
    int deg = rowStart[n + 1] - rs;   // real in-edges; self-loop at index deg
    float er0 = er[n * 2 + 0];
    float er1 = er[n * 2 + 1];

    // pass 1: leaky(e), track max; cache first-trip edge in regs
    float m0 = -3e38f, m1 = -3e38f;
    float e0reg = -3e38f, e1reg = -3e38f;
    int sreg = n;
    for (int i = lane; i <= deg; i += 64) {
        int s = (i == deg) ? n : csr[rs + i];
        float e0 = el[s * 2 + 0] + er0;
        e0 = (e0 >= 0.f) ? e0 : NEG_SLOPE * e0;
        float e1 = el[s * 2 + 1] + er1;
        e1 = (e1 >= 0.f) ? e1 : NEG_SLOPE * e1;
        if (i == lane) { sreg = s; e0reg = e0; e1reg = e1; }
        m0 = fmaxf(m0, e0);
        m1 = fmaxf(m1, e1);
    }
    for (int off = 32; off > 0; off >>= 1) {
        m0 = fmaxf(m0, __shfl_xor(m0, off));
        m1 = fmaxf(m1, __shfl_xor(m1, off));
    }

    // pass 2: sum of exp
    float s0 = 0.f, s1 = 0.f;
    if (deg < 64) {
        if (lane <= deg) {
            s0 = __expf(e0reg - m0);
            s1 = __expf(e1reg - m1);
        }
    } else {
        for (int i = lane; i <= deg; i += 64) {
            int s = (i == deg) ? n : csr[rs + i];
            float e0 = el[s * 2 + 0] + er0;
            e0 = (e0 >= 0.f) ? e0 : NEG_SLOPE * e0;
            float e1 = el[s * 2 + 1] + er1;
            e1 = (e1 >= 0.f) ? e1 : NEG_SLOPE * e1;
            s0 += __expf(e0 - m0);
            s1 += __expf(e1 - m1);
        }
    }
    for (int off = 32; off > 0; off >>= 1) {
        s0 += __shfl_xor(s0, off);
        s1 += __shfl_xor(s1, off);
    }
    float inv0 = 1.0f / s0, inv1 = 1.0f / s1;

    float mh = (lane < 32) ? m0 : m1;
    float invh = (lane < 32) ? inv0 : inv1;
    float erh = (lane < 32) ? er0 : er1;

    float a0 = 0.f, a1 = 0.f;
    if (deg < 64) {
        for (int j = 0; j <= deg; j++) {
            float e0j = __shfl(e0reg, j);
            float e1j = __shfl(e1reg, j);
            int sj = __shfl(sreg, j);
            float e = (lane < 32) ? e0j : e1j;
            float alpha = __expf(e - mh) * invh;
            float2 hv = ((const float2*)(h + (size_t)sj * 128))[lane];
            a0 += alpha * hv.x;
            a1 += alpha * hv.y;
        }
    } else {
        for (int j = 0; j <= deg; j++) {
            int sj = (j == deg) ? n : csr[rs + j];
            float elh = el[sj * 2 + (lane >> 5)];
            float e = elh + erh;
            e = (e >= 0.f) ? e : NEG_SLOPE * e;
            float alpha = __expf(e - mh) * invh;
            float2 hv = ((const float2*)(h + (size_t)sj * 128))[lane];
            a0 += alpha * hv.x;
            a1 += alpha * hv.y;
        }
    }

    float2 bv = ((const float2*)bias)[lane];
    a0 += bv.x;
    a1 += bv.y;
    if (RELU) {
        a0 = fmaxf(a0, 0.f);
        a1 = fmaxf(a1, 0.f);
    }
    ((float2*)(out + (size_t)n * 128))[lane] = make_float2(a0, a1);
}

// ---------------- launcher ----------------

static inline size_t align_up(size_t v, size_t a) { return (v + a - 1) & ~(a - 1); }

extern "C" void kernel_launch(void* const* d_in, const int* in_sizes, int n_in,
                              void* d_out, int out_size, void* d_ws, size_t ws_size,
                              hipStream_t stream) {
    const float* x   = (const float*)d_in[0];
    const int*   src = (const int*)d_in[1];
    const int*   dst = (const int*)d_in[2];
    const float* W1  = (const float*)d_in[3];
    const float* al1 = (const float*)d_in[4];
    const float* ar1 = (const float*)d_in[5];
    const float* b1  = (const float*)d_in[6];
    const float* W2  = (const float*)d_in[7];
    const float* al2 = (const float*)d_in[8];
    const float* ar2 = (const float*)d_in[9];
    const float* b2  = (const float*)d_in[10];
    float* out = (float*)d_out;

    const int N = in_sizes[0] / 128;
    const int E = in_sizes[1];
    const int NB = (N + SCAN_CHUNK - 1) / SCAN_CHUNK;   // 98 for N=100000

    // workspace carve-up
    char* ws = (char*)d_ws;
    size_t off = 0;
    float* bufA = (float*)(ws + off); off = align_up(off + (size_t)N * 128 * 4, 256);
    float* bufB = (float*)(ws + off); off = align_up(off + (size_t)N * 128 * 4, 256);
    float* el   = (float*)(ws + off); off = align_up(off + (size_t)N * 2 * 4, 256);
    float* er   = (float*)(ws + off); off = align_up(off + (size_t)N * 2 * 4, 256);
    int* rowStart = (int*)(ws + off); off = align_up(off + (size_t)(N + 1) * 4, 256);
    int* cursor   = (int*)(ws + off); off = align_up(off + (size_t)N * 4, 256);
    int* deg      = (int*)(ws + off); off = align_up(off + (size_t)N * 4, 256);
    int* bsum     = (int*)(ws + off); off = align_up(off + 256 * 4, 256);
    int* csr      = (int*)(ws + off); off = align_up(off + (size_t)E * 4, 256);

    // ---- CSR build (shared by both layers) ----
    hipMemsetAsync(deg, 0, (size_t)N * 4, stream);
    k_hist<<<(E + 255) / 256, 256, 0, stream>>>(dst, E, deg);
    k_block_sum<<<NB, 256, 0, stream>>>(deg, N, bsum);
    k_scan_bsum<<<1, 256, 0, stream>>>(bsum, NB);
    k_scan_final<<<NB, 256, 0, stream>>>(deg, N, bsum, rowStart, cursor, E);
    k_scatter<<<(E + 255) / 256, 256, 0, stream>>>(src, dst, E, cursor, csr);

    const int gemm_grid = (N + GEMM_ROWS - 1) / GEMM_ROWS;
    const int elr_grid = (2 * N + 255) / 256;
    const int agg_grid = (N + 3) / 4;

    // ---- layer 1 ----
    k_gemm128<<<gemm_grid, 256, 0, stream>>>(x, W1, bufA, N);
    k_elr<<<elr_grid, 256, 0, stream>>>(bufA, al1, ar1, el, er, N);
    k_agg<true><<<agg_grid, 256, 0, stream>>>(bufA, el, er, rowStart, csr, b1, bufB, N);

    // ---- layer 2 ----
    k_gemm128<<<gemm_grid, 256, 0, stream>>>(bufB, W2, bufA, N);
    k_elr<<<elr_grid, 256, 0, stream>>>(bufA, al2, ar2, el, er, N);
    k_agg<false><<<agg_grid, 256, 0, stream>>>(bufA, el, er, rowStart, csr, b2, out, N);
}

// Round 2
// 637.212 us; speedup vs baseline: 5.7577x; 5.7577x over previous
//
#include <hip/hip_runtime.h>
#include <hip/hip_bf16.h>

// 2-layer GAT, H=2 heads, D=64 per head, F_IN=128, all fp32.
// Pipeline: CSR build (by dst) -> [GEMM -> el/er -> aggregate] x2.

#define NEG_SLOPE 0.2f
#define SCAN_CHUNK 1024

// ---------------- CSR build ----------------

__global__ void k_hist(const int* __restrict__ dst, int E, int* __restrict__ deg) {
    int e = blockIdx.x * 256 + threadIdx.x;
    if (e < E) atomicAdd(&deg[dst[e]], 1);
}

__global__ void k_block_sum(const int* __restrict__ deg, int n, int* __restrict__ bsum) {
    __shared__ int sdata[256];
    int base = blockIdx.x * SCAN_CHUNK;
    int t = threadIdx.x;
    int s = 0;
    for (int j = t; j < SCAN_CHUNK; j += 256) {
        int idx = base + j;
        s += (idx < n) ? deg[idx] : 0;
    }
    sdata[t] = s;
    __syncthreads();
    for (int off = 128; off > 0; off >>= 1) {
        if (t < off) sdata[t] += sdata[t + off];
        __syncthreads();
    }
    if (t == 0) bsum[blockIdx.x] = sdata[0];
}

__global__ void k_scan_bsum(int* __restrict__ bsum, int nb) {
    __shared__ int sd[256];
    int t = threadIdx.x;
    sd[t] = (t < nb) ? bsum[t] : 0;
    __syncthreads();
    for (int off = 1; off < 256; off <<= 1) {
        int v = (t >= off) ? sd[t - off] : 0;
        __syncthreads();
        sd[t] += v;
        __syncthreads();
    }
    if (t < nb) bsum[t] = (t == 0) ? 0 : sd[t - 1];
}

__global__ void k_scan_final(const int* __restrict__ deg, int n,
                             const int* __restrict__ bsum,
                             int* __restrict__ rowStart, int* __restrict__ cursor, int E) {
    __shared__ int sd[256];
    int base = blockIdx.x * SCAN_CHUNK;
    int t = threadIdx.x;
    int idx0 = base + t * 4;
    int v[4];
    int s = 0;
    for (int j = 0; j < 4; j++) {
        int idx = idx0 + j;
        v[j] = (idx < n) ? deg[idx] : 0;
        s += v[j];
    }
    sd[t] = s;
    __syncthreads();
    for (int off = 1; off < 256; off <<= 1) {
        int x = (t >= off) ? sd[t - off] : 0;
        __syncthreads();
        sd[t] += x;
        __syncthreads();
    }
    int running = bsum[blockIdx.x] + ((t == 0) ? 0 : sd[t - 1]);
    for (int j = 0; j < 4; j++) {
        int idx = idx0 + j;
        if (idx < n) {
            rowStart[idx] = running;
            cursor[idx] = running;
        }
        running += v[j];
    }
    if (blockIdx.x == 0 && t == 0) rowStart[n] = E;
}

__global__ void k_scatter(const int* __restrict__ src, const int* __restrict__ dst, int E,
                          int* __restrict__ cursor, int* __restrict__ csr) {
    int e = blockIdx.x * 256 + threadIdx.x;
    if (e < E) {
        int d = dst[e];
        int p = atomicAdd(&cursor[d], 1);
        csr[p] = src[e];
    }
}

// ---------------- GEMM: C[M][128] = A[M][128] @ W[128][128] (fp32) ----------------
// 256 threads/block, 64-row tile. Per thread: 8 rows x 4 cols (acc = 8 float4).
// Inner loop processes k in groups of 4 with float4 LDS reads; unroll capped
// at 2 so the live set stays ~90 VGPR (R1 version spilled at 256 VGPR ->
// 2.2GB scratch fetch, 1750us).

#define GEMM_ROWS 64
__global__ __launch_bounds__(256, 4) void k_gemm128(const float* __restrict__ A,
                                                    const float* __restrict__ W,
                                                    float* __restrict__ C, int M) {
    __shared__ float xs[GEMM_ROWS][128];   // 32 KB
    __shared__ float ws[32][128];          // 16 KB
    int row0 = blockIdx.x * GEMM_ROWS;
    int t = threadIdx.x;

    // stage x tile: 2048 float4, 8 per thread, coalesced
    for (int j = 0; j < 8; j++) {
        int f4 = t + j * 256;
        int r = f4 >> 5;
        int c4 = f4 & 31;
        float4 v = make_float4(0.f, 0.f, 0.f, 0.f);
        int gr = row0 + r;
        if (gr < M) v = ((const float4*)(A + (size_t)gr * 128))[c4];
        ((float4*)&xs[r][0])[c4] = v;
    }

    int tc = t & 31;   // col group (4 cols)
    int tr = t >> 5;   // row group (8 rows)
    float4 acc[8];
    #pragma unroll
    for (int i = 0; i < 8; i++) acc[i] = make_float4(0.f, 0.f, 0.f, 0.f);

    for (int kt = 0; kt < 4; kt++) {
        __syncthreads();
        // stage W rows [kt*32, kt*32+32): 1024 float4, 4 per thread
        for (int j = 0; j < 4; j++) {
            int f4 = t + j * 256;
            int r = f4 >> 5;
            int c4 = f4 & 31;
            ((float4*)&ws[r][0])[c4] = ((const float4*)(W + (size_t)(kt * 32 + r) * 128))[c4];
        }
        __syncthreads();
        #pragma unroll 2
        for (int k4 = 0; k4 < 8; k4++) {
            int k = kt * 32 + k4 * 4;
            float4 w0 = ((float4*)&ws[k4 * 4 + 0][0])[tc];
            float4 w1 = ((float4*)&ws[k4 * 4 + 1][0])[tc];
            float4 w2 = ((float4*)&ws[k4 * 4 + 2][0])[tc];
            float4 w3 = ((float4*)&ws[k4 * 4 + 3][0])[tc];
            #pragma unroll
            for (int i = 0; i < 8; i++) {
                float4 xv = *((float4*)&xs[tr * 8 + i][k]);
                acc[i].x += xv.x * w0.x + xv.y * w1.x + xv.z * w2.x + xv.w * w3.x;
                acc[i].y += xv.x * w0.y + xv.y * w1.y + xv.z * w2.y + xv.w * w3.y;
                acc[i].z += xv.x * w0.z + xv.y * w1.z + xv.z * w2.z + xv.w * w3.z;
                acc[i].w += xv.x * w0.w + xv.y * w1.w + xv.z * w2.w + xv.w * w3.w;
            }
        }
    }
    #pragma unroll
    for (int i = 0; i < 8; i++) {
        int gr = row0 + tr * 8 + i;
        if (gr < M) ((float4*)(C + (size_t)gr * 128))[tc] = acc[i];
    }
}

// ---------------- el/er: [N,2] attention projections ----------------

__global__ void k_elr(const float* __restrict__ h, const float* __restrict__ al,
                      const float* __restrict__ ar, float* __restrict__ el,
                      float* __restrict__ er, int N) {
    int t = blockIdx.x * 256 + threadIdx.x;
    int n = t >> 1;
    int hd = t & 1;
    if (n >= N) return;
    const float* hp = h + (size_t)n * 128 + hd * 64;
    const float* alp = al + hd * 64;
    const float* arp = ar + hd * 64;
    float sl = 0.f, sr = 0.f;
    for (int j = 0; j < 16; j++) {
        float4 hv = ((const float4*)hp)[j];
        float4 av = ((const float4*)alp)[j];
        float4 rv = ((const float4*)arp)[j];
        sl += hv.x * av.x + hv.y * av.y + hv.z * av.z + hv.w * av.w;
        sr += hv.x * rv.x + hv.y * rv.y + hv.z * rv.z + hv.w * rv.w;
    }
    el[n * 2 + hd] = sl;
    er[n * 2 + hd] = sr;
}

// ---------------- aggregate: per-node edge softmax + weighted sum ----------------
// One wave (64 lanes) per node. Lane l owns output dims 2l, 2l+1.

template <bool RELU>
__global__ __launch_bounds__(256) void k_agg(const float* __restrict__ h,
                                             const float* __restrict__ el,
                                             const float* __restrict__ er,
                                             const int* __restrict__ rowStart,
                                             const int* __restrict__ csr,
                                             const float* __restrict__ bias,
                                             float* __restrict__ out, int N) {
    int wave = threadIdx.x >> 6;
    int lane = threadIdx.x & 63;
    int n = blockIdx.x * 4 + wave;
    if (n >= N) return;

    int rs = rowStart[n];
    int deg = rowStart[n + 1] - rs;   // real in-edges; self-loop at index deg
    float er0 = er[n * 2 + 0];
    float er1 = er[n * 2 + 1];

    float m0 = -3e38f, m1 = -3e38f;
    float e0reg = -3e38f, e1reg = -3e38f;
    int sreg = n;
    for (int i = lane; i <= deg; i += 64) {
        int s = (i == deg) ? n : csr[rs + i];
        float e0 = el[s * 2 + 0] + er0;
        e0 = (e0 >= 0.f) ? e0 : NEG_SLOPE * e0;
        float e1 = el[s * 2 + 1] + er1;
        e1 = (e1 >= 0.f) ? e1 : NEG_SLOPE * e1;
        if (i == lane) { sreg = s; e0reg = e0; e1reg = e1; }
        m0 = fmaxf(m0, e0);
        m1 = fmaxf(m1, e1);
    }
    for (int off = 32; off > 0; off >>= 1) {
        m0 = fmaxf(m0, __shfl_xor(m0, off));
        m1 = fmaxf(m1, __shfl_xor(m1, off));
    }

    float s0 = 0.f, s1 = 0.f;
    if (deg < 64) {
        if (lane <= deg) {
            s0 = __expf(e0reg - m0);
            s1 = __expf(e1reg - m1);
        }
    } else {
        for (int i = lane; i <= deg; i += 64) {
            int s = (i == deg) ? n : csr[rs + i];
            float e0 = el[s * 2 + 0] + er0;
            e0 = (e0 >= 0.f) ? e0 : NEG_SLOPE * e0;
            float e1 = el[s * 2 + 1] + er1;
            e1 = (e1 >= 0.f) ? e1 : NEG_SLOPE * e1;
            s0 += __expf(e0 - m0);
            s1 += __expf(e1 - m1);
        }
    }
    for (int off = 32; off > 0; off >>= 1) {
        s0 += __shfl_xor(s0, off);
        s1 += __shfl_xor(s1, off);
    }
    float inv0 = 1.0f / s0, inv1 = 1.0f / s1;

    float mh = (lane < 32) ? m0 : m1;
    float invh = (lane < 32) ? inv0 : inv1;
    float erh = (lane < 32) ? er0 : er1;

    float a0 = 0.f, a1 = 0.f;
    if (deg < 64) {
        for (int j = 0; j <= deg; j++) {
            float e0j = __shfl(e0reg, j);
            float e1j = __shfl(e1reg, j);
            int sj = __shfl(sreg, j);
            float e = (lane < 32) ? e0j : e1j;
            float alpha = __expf(e - mh) * invh;
            float2 hv = ((const float2*)(h + (size_t)sj * 128))[lane];
            a0 += alpha * hv.x;
            a1 += alpha * hv.y;
        }
    } else {
        for (int j = 0; j <= deg; j++) {
            int sj = (j == deg) ? n : csr[rs + j];
            float elh = el[sj * 2 + (lane >> 5)];
            float e = elh + erh;
            e = (e >= 0.f) ? e : NEG_SLOPE * e;
            float alpha = __expf(e - mh) * invh;
            float2 hv = ((const float2*)(h + (size_t)sj * 128))[lane];
            a0 += alpha * hv.x;
            a1 += alpha * hv.y;
        }
    }

    float2 bv = ((const float2*)bias)[lane];
    a0 += bv.x;
    a1 += bv.y;
    if (RELU) {
        a0 = fmaxf(a0, 0.f);
        a1 = fmaxf(a1, 0.f);
    }
    ((float2*)(out + (size_t)n * 128))[lane] = make_float2(a0, a1);
}

// ---------------- launcher ----------------

static inline size_t align_up(size_t v, size_t a) { return (v + a - 1) & ~(a - 1); }

extern "C" void kernel_launch(void* const* d_in, const int* in_sizes, int n_in,
                              void* d_out, int out_size, void* d_ws, size_t ws_size,
                              hipStream_t stream) {
    const float* x   = (const float*)d_in[0];
    const int*   src = (const int*)d_in[1];
    const int*   dst = (const int*)d_in[2];
    const float* W1  = (const float*)d_in[3];
    const float* al1 = (const float*)d_in[4];
    const float* ar1 = (const float*)d_in[5];
    const float* b1  = (const float*)d_in[6];
    const float* W2  = (const float*)d_in[7];
    const float* al2 = (const float*)d_in[8];
    const float* ar2 = (const float*)d_in[9];
    const float* b2  = (const float*)d_in[10];
    float* out = (float*)d_out;

    const int N = in_sizes[0] / 128;
    const int E = in_sizes[1];
    const int NB = (N + SCAN_CHUNK - 1) / SCAN_CHUNK;

    char* ws = (char*)d_ws;
    size_t off = 0;
    float* bufA = (float*)(ws + off); off = align_up(off + (size_t)N * 128 * 4, 256);
    float* bufB = (float*)(ws + off); off = align_up(off + (size_t)N * 128 * 4, 256);
    float* el   = (float*)(ws + off); off = align_up(off + (size_t)N * 2 * 4, 256);
    float* er   = (float*)(ws + off); off = align_up(off + (size_t)N * 2 * 4, 256);
    int* rowStart = (int*)(ws + off); off = align_up(off + (size_t)(N + 1) * 4, 256);
    int* cursor   = (int*)(ws + off); off = align_up(off + (size_t)N * 4, 256);
    int* deg      = (int*)(ws + off); off = align_up(off + (size_t)N * 4, 256);
    int* bsum     = (int*)(ws + off); off = align_up(off + 256 * 4, 256);
    int* csr      = (int*)(ws + off); off = align_up(off + (size_t)E * 4, 256);

    hipMemsetAsync(deg, 0, (size_t)N * 4, stream);
    k_hist<<<(E + 255) / 256, 256, 0, stream>>>(dst, E, deg);
    k_block_sum<<<NB, 256, 0, stream>>>(deg, N, bsum);
    k_scan_bsum<<<1, 256, 0, stream>>>(bsum, NB);
    k_scan_final<<<NB, 256, 0, stream>>>(deg, N, bsum, rowStart, cursor, E);
    k_scatter<<<(E + 255) / 256, 256, 0, stream>>>(src, dst, E, cursor, csr);

    const int gemm_grid = (N + GEMM_ROWS - 1) / GEMM_ROWS;
    const int elr_grid = (2 * N + 255) / 256;
    const int agg_grid = (N + 3) / 4;

    k_gemm128<<<gemm_grid, 256, 0, stream>>>(x, W1, bufA, N);
    k_elr<<<elr_grid, 256, 0, stream>>>(bufA, al1, ar1, el, er, N);
    k_agg<true><<<agg_grid, 256, 0, stream>>>(bufA, el, er, rowStart, csr, b1, bufB, N);

    k_gemm128<<<gemm_grid, 256, 0, stream>>>(bufB, W2, bufA, N);
    k_elr<<<elr_grid, 256, 0, stream>>>(bufA, al2, ar2, el, er, N);
    k_agg<false><<<agg_grid, 256, 0, stream>>>(bufA, el, er, rowStart, csr, b2, out, N);
}

// Round 3
// 590.259 us; speedup vs baseline: 6.2157x; 1.0795x over previous
//
#include <hip/hip_runtime.h>
#include <hip/hip_bf16.h>

// 2-layer GAT, H=2 heads, D=64 per head, F_IN=128, all fp32.
// Pipeline: CSR build (by dst) -> [GEMM(+el/er epilogue) -> aggregate] x2.

#define NEG_SLOPE 0.2f
#define SCAN_CHUNK 1024

// ---------------- CSR build ----------------

__global__ void k_hist(const int* __restrict__ dst, int E, int* __restrict__ deg) {
    int e = blockIdx.x * 256 + threadIdx.x;
    if (e < E) atomicAdd(&deg[dst[e]], 1);
}

__global__ void k_block_sum(const int* __restrict__ deg, int n, int* __restrict__ bsum) {
    __shared__ int sdata[256];
    int base = blockIdx.x * SCAN_CHUNK;
    int t = threadIdx.x;
    int s = 0;
    for (int j = t; j < SCAN_CHUNK; j += 256) {
        int idx = base + j;
        s += (idx < n) ? deg[idx] : 0;
    }
    sdata[t] = s;
    __syncthreads();
    for (int off = 128; off > 0; off >>= 1) {
        if (t < off) sdata[t] += sdata[t + off];
        __syncthreads();
    }
    if (t == 0) bsum[blockIdx.x] = sdata[0];
}

__global__ void k_scan_bsum(int* __restrict__ bsum, int nb) {
    __shared__ int sd[256];
    int t = threadIdx.x;
    sd[t] = (t < nb) ? bsum[t] : 0;
    __syncthreads();
    for (int off = 1; off < 256; off <<= 1) {
        int v = (t >= off) ? sd[t - off] : 0;
        __syncthreads();
        sd[t] += v;
        __syncthreads();
    }
    if (t < nb) bsum[t] = (t == 0) ? 0 : sd[t - 1];
}

__global__ void k_scan_final(const int* __restrict__ deg, int n,
                             const int* __restrict__ bsum,
                             int* __restrict__ rowStart, int* __restrict__ cursor, int E) {
    __shared__ int sd[256];
    int base = blockIdx.x * SCAN_CHUNK;
    int t = threadIdx.x;
    int idx0 = base + t * 4;
    int v[4];
    int s = 0;
    for (int j = 0; j < 4; j++) {
        int idx = idx0 + j;
        v[j] = (idx < n) ? deg[idx] : 0;
        s += v[j];
    }
    sd[t] = s;
    __syncthreads();
    for (int off = 1; off < 256; off <<= 1) {
        int x = (t >= off) ? sd[t - off] : 0;
        __syncthreads();
        sd[t] += x;
        __syncthreads();
    }
    int running = bsum[blockIdx.x] + ((t == 0) ? 0 : sd[t - 1]);
    for (int j = 0; j < 4; j++) {
        int idx = idx0 + j;
        if (idx < n) {
            rowStart[idx] = running;
            cursor[idx] = running;
        }
        running += v[j];
    }
    if (blockIdx.x == 0 && t == 0) rowStart[n] = E;
}

__global__ void k_scatter(const int* __restrict__ src, const int* __restrict__ dst, int E,
                          int* __restrict__ cursor, int* __restrict__ csr) {
    int e = blockIdx.x * 256 + threadIdx.x;
    if (e < E) {
        int d = dst[e];
        int p = atomicAdd(&cursor[d], 1);
        csr[p] = src[e];
    }
}

// ---------------- GEMM: C[M][128] = A[M][128] @ W[128][128] (fp32) ----------------
// + fused el/er epilogue (el[n,h] = dot(h_row, al[h]), er likewise) computed
// from the acc registers -- saves re-reading 51MB of h per layer.

#define GEMM_ROWS 64
__global__ __launch_bounds__(256, 4) void k_gemm128(const float* __restrict__ A,
                                                    const float* __restrict__ W,
                                                    float* __restrict__ C,
                                                    const float* __restrict__ al,
                                                    const float* __restrict__ ar,
                                                    float* __restrict__ el,
                                                    float* __restrict__ er, int M) {
    __shared__ float xs[GEMM_ROWS][128];   // 32 KB
    __shared__ float ws[32][128];          // 16 KB
    int row0 = blockIdx.x * GEMM_ROWS;
    int t = threadIdx.x;

    for (int j = 0; j < 8; j++) {
        int f4 = t + j * 256;
        int r = f4 >> 5;
        int c4 = f4 & 31;
        float4 v = make_float4(0.f, 0.f, 0.f, 0.f);
        int gr = row0 + r;
        if (gr < M) v = ((const float4*)(A + (size_t)gr * 128))[c4];
        ((float4*)&xs[r][0])[c4] = v;
    }

    int tc = t & 31;   // col group (4 cols: dims 4tc..4tc+3)
    int tr = t >> 5;   // row group (8 rows)
    float4 acc[8];
    #pragma unroll
    for (int i = 0; i < 8; i++) acc[i] = make_float4(0.f, 0.f, 0.f, 0.f);

    for (int kt = 0; kt < 4; kt++) {
        __syncthreads();
        for (int j = 0; j < 4; j++) {
            int f4 = t + j * 256;
            int r = f4 >> 5;
            int c4 = f4 & 31;
            ((float4*)&ws[r][0])[c4] = ((const float4*)(W + (size_t)(kt * 32 + r) * 128))[c4];
        }
        __syncthreads();
        #pragma unroll 2
        for (int k4 = 0; k4 < 8; k4++) {
            int k = kt * 32 + k4 * 4;
            float4 w0 = ((float4*)&ws[k4 * 4 + 0][0])[tc];
            float4 w1 = ((float4*)&ws[k4 * 4 + 1][0])[tc];
            float4 w2 = ((float4*)&ws[k4 * 4 + 2][0])[tc];
            float4 w3 = ((float4*)&ws[k4 * 4 + 3][0])[tc];
            #pragma unroll
            for (int i = 0; i < 8; i++) {
                float4 xv = *((float4*)&xs[tr * 8 + i][k]);
                acc[i].x += xv.x * w0.x + xv.y * w1.x + xv.z * w2.x + xv.w * w3.x;
                acc[i].y += xv.x * w0.y + xv.y * w1.y + xv.z * w2.y + xv.w * w3.y;
                acc[i].z += xv.x * w0.z + xv.y * w1.z + xv.z * w2.z + xv.w * w3.z;
                acc[i].w += xv.x * w0.w + xv.y * w1.w + xv.z * w2.w + xv.w * w3.w;
            }
        }
    }

    // C store
    #pragma unroll
    for (int i = 0; i < 8; i++) {
        int gr = row0 + tr * 8 + i;
        if (gr < M) ((float4*)(C + (size_t)gr * 128))[tc] = acc[i];
    }

    // el/er epilogue: al/ar flat [128] match C's column layout (head = tc>=16).
    float4 alv = ((const float4*)al)[tc];
    float4 arv = ((const float4*)ar)[tc];
    #pragma unroll
    for (int i = 0; i < 8; i++) {
        float pl = acc[i].x * alv.x + acc[i].y * alv.y + acc[i].z * alv.z + acc[i].w * alv.w;
        float pr = acc[i].x * arv.x + acc[i].y * arv.y + acc[i].z * arv.z + acc[i].w * arv.w;
        pl += __shfl_xor(pl, 1);  pr += __shfl_xor(pr, 1);
        pl += __shfl_xor(pl, 2);  pr += __shfl_xor(pr, 2);
        pl += __shfl_xor(pl, 4);  pr += __shfl_xor(pr, 4);
        pl += __shfl_xor(pl, 8);  pr += __shfl_xor(pr, 8);
        int gr = row0 + tr * 8 + i;
        if ((tc & 15) == 0 && gr < M) {
            int hd = tc >> 4;
            el[gr * 2 + hd] = pl;
            er[gr * 2 + hd] = pr;
        }
    }
}

// ---------------- aggregate: per-node edge softmax + weighted sum ----------------
// One wave per node. Fast path (deg<64): lane i holds edge i's (src, alpha0,
// alpha1); accumulate processes 2 edges/iter (lanes 0-31 even edges, 32-63 odd
// edges, float4/lane), then a cross-half shfl combine.

template <bool RELU>
__global__ __launch_bounds__(256) void k_agg(const float* __restrict__ h,
                                             const float* __restrict__ el,
                                             const float* __restrict__ er,
                                             const int* __restrict__ rowStart,
                                             const int* __restrict__ csr,
                                             const float* __restrict__ bias,
                                             float* __restrict__ out, int N) {
    int wave = threadIdx.x >> 6;
    int lane = threadIdx.x & 63;
    int n = blockIdx.x * 4 + wave;
    if (n >= N) return;

    int rs = rowStart[n];
    int deg = rowStart[n + 1] - rs;   // in-edges; self-loop at index deg
    float er0 = er[n * 2 + 0];
    float er1 = er[n * 2 + 1];

    if (deg < 64) {
        // ---- fast path: cnt = deg+1 <= 64 edges, one per lane ----
        int sreg = n;
        float e0reg = -3e38f, e1reg = -3e38f;
        if (lane <= deg) {
            sreg = (lane == deg) ? n : csr[rs + lane];
            float e0 = el[sreg * 2 + 0] + er0;
            e0reg = (e0 >= 0.f) ? e0 : NEG_SLOPE * e0;
            float e1 = el[sreg * 2 + 1] + er1;
            e1reg = (e1 >= 0.f) ? e1 : NEG_SLOPE * e1;
        }
        float m0 = e0reg, m1 = e1reg;
        for (int off = 32; off > 0; off >>= 1) {
            m0 = fmaxf(m0, __shfl_xor(m0, off));
            m1 = fmaxf(m1, __shfl_xor(m1, off));
        }
        float ex0 = 0.f, ex1 = 0.f;
        if (lane <= deg) {
            ex0 = __expf(e0reg - m0);
            ex1 = __expf(e1reg - m1);
        }
        float s0 = ex0, s1 = ex1;
        for (int off = 32; off > 0; off >>= 1) {
            s0 += __shfl_xor(s0, off);
            s1 += __shfl_xor(s1, off);
        }
        float alpha0 = ex0 * (1.0f / s0);   // 0 for lanes > deg
        float alpha1 = ex1 * (1.0f / s1);

        int c = lane & 31;        // dim block: dims 4c..4c+3
        int half = lane >> 5;     // 0: even edges, 1: odd edges
        bool head1 = (c >= 16);
        float4 acc = make_float4(0.f, 0.f, 0.f, 0.f);
        int cnt = deg + 1;
        int iters = (cnt + 1) >> 1;
        #pragma unroll 2
        for (int kk = 0; kk < iters; ++kk) {
            int j = 2 * kk + half;            // j>=cnt lanes contribute alpha=0, s=n (safe)
            float a0b = __shfl(alpha0, j);
            float a1b = __shfl(alpha1, j);
            int   sj  = __shfl(sreg, j);
            float a   = head1 ? a1b : a0b;
            float4 hv = ((const float4*)(h + (size_t)sj * 128))[c];
            acc.x += a * hv.x;
            acc.y += a * hv.y;
            acc.z += a * hv.z;
            acc.w += a * hv.w;
        }
        // combine even/odd halves
        acc.x += __shfl_xor(acc.x, 32);
        acc.y += __shfl_xor(acc.y, 32);
        acc.z += __shfl_xor(acc.z, 32);
        acc.w += __shfl_xor(acc.w, 32);
        if (lane < 32) {
            float4 bv = ((const float4*)bias)[c];
            acc.x += bv.x; acc.y += bv.y; acc.z += bv.z; acc.w += bv.w;
            if (RELU) {
                acc.x = fmaxf(acc.x, 0.f); acc.y = fmaxf(acc.y, 0.f);
                acc.z = fmaxf(acc.z, 0.f); acc.w = fmaxf(acc.w, 0.f);
            }
            ((float4*)(out + (size_t)n * 128))[c] = acc;
        }
    } else {
        // ---- general path (deg >= 64): strided passes, float2 per lane ----
        float m0 = -3e38f, m1 = -3e38f;
        for (int i = lane; i <= deg; i += 64) {
            int s = (i == deg) ? n : csr[rs + i];
            float e0 = el[s * 2 + 0] + er0;
            e0 = (e0 >= 0.f) ? e0 : NEG_SLOPE * e0;
            float e1 = el[s * 2 + 1] + er1;
            e1 = (e1 >= 0.f) ? e1 : NEG_SLOPE * e1;
            m0 = fmaxf(m0, e0);
            m1 = fmaxf(m1, e1);
        }
        for (int off = 32; off > 0; off >>= 1) {
            m0 = fmaxf(m0, __shfl_xor(m0, off));
            m1 = fmaxf(m1, __shfl_xor(m1, off));
        }
        float s0 = 0.f, s1 = 0.f;
        for (int i = lane; i <= deg; i += 64) {
            int s = (i == deg) ? n : csr[rs + i];
            float e0 = el[s * 2 + 0] + er0;
            e0 = (e0 >= 0.f) ? e0 : NEG_SLOPE * e0;
            float e1 = el[s * 2 + 1] + er1;
            e1 = (e1 >= 0.f) ? e1 : NEG_SLOPE * e1;
            s0 += __expf(e0 - m0);
            s1 += __expf(e1 - m1);
        }
        for (int off = 32; off > 0; off >>= 1) {
            s0 += __shfl_xor(s0, off);
            s1 += __shfl_xor(s1, off);
        }
        float inv0 = 1.0f / s0, inv1 = 1.0f / s1;
        float mh = (lane < 32) ? m0 : m1;
        float invh = (lane < 32) ? inv0 : inv1;
        float erh = (lane < 32) ? er0 : er1;
        float a0 = 0.f, a1 = 0.f;
        for (int j = 0; j <= deg; j++) {
            int sj = (j == deg) ? n : csr[rs + j];
            float elh = el[sj * 2 + (lane >> 5)];
            float e = elh + erh;
            e = (e >= 0.f) ? e : NEG_SLOPE * e;
            float alpha = __expf(e - mh) * invh;
            float2 hv = ((const float2*)(h + (size_t)sj * 128))[lane];
            a0 += alpha * hv.x;
            a1 += alpha * hv.y;
        }
        float2 bv = ((const float2*)bias)[lane];
        a0 += bv.x;
        a1 += bv.y;
        if (RELU) {
            a0 = fmaxf(a0, 0.f);
            a1 = fmaxf(a1, 0.f);
        }
        ((float2*)(out + (size_t)n * 128))[lane] = make_float2(a0, a1);
    }
}

// ---------------- launcher ----------------

static inline size_t align_up(size_t v, size_t a) { return (v + a - 1) & ~(a - 1); }

extern "C" void kernel_launch(void* const* d_in, const int* in_sizes, int n_in,
                              void* d_out, int out_size, void* d_ws, size_t ws_size,
                              hipStream_t stream) {
    const float* x   = (const float*)d_in[0];
    const int*   src = (const int*)d_in[1];
    const int*   dst = (const int*)d_in[2];
    const float* W1  = (const float*)d_in[3];
    const float* al1 = (const float*)d_in[4];
    const float* ar1 = (const float*)d_in[5];
    const float* b1  = (const float*)d_in[6];
    const float* W2  = (const float*)d_in[7];
    const float* al2 = (const float*)d_in[8];
    const float* ar2 = (const float*)d_in[9];
    const float* b2  = (const float*)d_in[10];
    float* out = (float*)d_out;

    const int N = in_sizes[0] / 128;
    const int E = in_sizes[1];
    const int NB = (N + SCAN_CHUNK - 1) / SCAN_CHUNK;

    char* ws = (char*)d_ws;
    size_t off = 0;
    float* bufA = (float*)(ws + off); off = align_up(off + (size_t)N * 128 * 4, 256);
    float* bufB = (float*)(ws + off); off = align_up(off + (size_t)N * 128 * 4, 256);
    float* el   = (float*)(ws + off); off = align_up(off + (size_t)N * 2 * 4, 256);
    float* er   = (float*)(ws + off); off = align_up(off + (size_t)N * 2 * 4, 256);
    int* rowStart = (int*)(ws + off); off = align_up(off + (size_t)(N + 1) * 4, 256);
    int* cursor   = (int*)(ws + off); off = align_up(off + (size_t)N * 4, 256);
    int* deg      = (int*)(ws + off); off = align_up(off + (size_t)N * 4, 256);
    int* bsum     = (int*)(ws + off); off = align_up(off + 256 * 4, 256);
    int* csr      = (int*)(ws + off); off = align_up(off + (size_t)E * 4, 256);

    hipMemsetAsync(deg, 0, (size_t)N * 4, stream);
    k_hist<<<(E + 255) / 256, 256, 0, stream>>>(dst, E, deg);
    k_block_sum<<<NB, 256, 0, stream>>>(deg, N, bsum);
    k_scan_bsum<<<1, 256, 0, stream>>>(bsum, NB);
    k_scan_final<<<NB, 256, 0, stream>>>(deg, N, bsum, rowStart, cursor, E);
    k_scatter<<<(E + 255) / 256, 256, 0, stream>>>(src, dst, E, cursor, csr);

    const int gemm_grid = (N + GEMM_ROWS - 1) / GEMM_ROWS;
    const int agg_grid = (N + 3) / 4;

    k_gemm128<<<gemm_grid, 256, 0, stream>>>(x, W1, bufA, al1, ar1, el, er, N);
    k_agg<true><<<agg_grid, 256, 0, stream>>>(bufA, el, er, rowStart, csr, b1, bufB, N);

    k_gemm128<<<gemm_grid, 256, 0, stream>>>(bufB, W2, bufA, al2, ar2, el, er, N);
    k_agg<false><<<agg_grid, 256, 0, stream>>>(bufA, el, er, rowStart, csr, b2, out, N);
}

// Round 4
// 487.408 us; speedup vs baseline: 7.5273x; 1.2110x over previous
//
#include <hip/hip_runtime.h>
#include <hip/hip_fp16.h>

// 2-layer GAT, H=2 heads, D=64 per head, F_IN=128.
// CSR build (by dst) -> [GEMM(fp32, fused el/er + fp16 h-copy) -> aggregate] x2.
// GEMM never stores fp32 C: aggregation gathers from the fp16 copy (hb);
// layer-2 GEMM input is aggregate's own fp32 output.

#define NEG_SLOPE 0.2f
#define SCAN_CHUNK 1024

// ---------------- CSR build ----------------

__global__ void k_hist(const int* __restrict__ dst, int E, int* __restrict__ deg) {
    int e = blockIdx.x * 256 + threadIdx.x;
    if (e < E) atomicAdd(&deg[dst[e]], 1);
}

__global__ void k_block_sum(const int* __restrict__ deg, int n, int* __restrict__ bsum) {
    __shared__ int sdata[256];
    int base = blockIdx.x * SCAN_CHUNK;
    int t = threadIdx.x;
    int s = 0;
    for (int j = t; j < SCAN_CHUNK; j += 256) {
        int idx = base + j;
        s += (idx < n) ? deg[idx] : 0;
    }
    sdata[t] = s;
    __syncthreads();
    for (int off = 128; off > 0; off >>= 1) {
        if (t < off) sdata[t] += sdata[t + off];
        __syncthreads();
    }
    if (t == 0) bsum[blockIdx.x] = sdata[0];
}

__global__ void k_scan_bsum(int* __restrict__ bsum, int nb) {
    __shared__ int sd[256];
    int t = threadIdx.x;
    sd[t] = (t < nb) ? bsum[t] : 0;
    __syncthreads();
    for (int off = 1; off < 256; off <<= 1) {
        int v = (t >= off) ? sd[t - off] : 0;
        __syncthreads();
        sd[t] += v;
        __syncthreads();
    }
    if (t < nb) bsum[t] = (t == 0) ? 0 : sd[t - 1];
}

__global__ void k_scan_final(const int* __restrict__ deg, int n,
                             const int* __restrict__ bsum,
                             int* __restrict__ rowStart, int* __restrict__ cursor, int E) {
    __shared__ int sd[256];
    int base = blockIdx.x * SCAN_CHUNK;
    int t = threadIdx.x;
    int idx0 = base + t * 4;
    int v[4];
    int s = 0;
    for (int j = 0; j < 4; j++) {
        int idx = idx0 + j;
        v[j] = (idx < n) ? deg[idx] : 0;
        s += v[j];
    }
    sd[t] = s;
    __syncthreads();
    for (int off = 1; off < 256; off <<= 1) {
        int x = (t >= off) ? sd[t - off] : 0;
        __syncthreads();
        sd[t] += x;
        __syncthreads();
    }
    int running = bsum[blockIdx.x] + ((t == 0) ? 0 : sd[t - 1]);
    for (int j = 0; j < 4; j++) {
        int idx = idx0 + j;
        if (idx < n) {
            rowStart[idx] = running;
            cursor[idx] = running;
        }
        running += v[j];
    }
    if (blockIdx.x == 0 && t == 0) rowStart[n] = E;
}

__global__ void k_scatter(const int* __restrict__ src, const int* __restrict__ dst, int E,
                          int* __restrict__ cursor, int* __restrict__ csr) {
    int e = blockIdx.x * 256 + threadIdx.x;
    if (e < E) {
        int d = dst[e];
        int p = atomicAdd(&cursor[d], 1);
        csr[p] = src[e];
    }
}

// ---------------- fused GEMM ----------------
// h = A[M,128] @ W[128,128]; outputs: hb (fp16 copy of h, for gathers),
// el/er [M,2] attention projections. fp32 C is never materialized.
// W staged via global_load_lds into double-buffered LDS (BK=16), 1 barrier/stage.

__device__ __forceinline__ void g2l16(const float* g, void* l) {
    __builtin_amdgcn_global_load_lds((const __attribute__((address_space(1))) void*)g,
                                     (__attribute__((address_space(3))) void*)l, 16, 0, 0);
}

#define BK 16
__global__ __launch_bounds__(256, 4) void k_gemm_fused(const float* __restrict__ A,
                                                       const float* __restrict__ W,
                                                       __half* __restrict__ hb,
                                                       const float* __restrict__ al,
                                                       const float* __restrict__ ar,
                                                       float* __restrict__ el,
                                                       float* __restrict__ er, int M) {
    __shared__ float xs[64][128];        // 32 KB
    __shared__ float ws[2][BK][128];     // 16 KB (double-buffered)
    int row0 = blockIdx.x * 64;
    int t = threadIdx.x;

    // issue A-tile loads: 2048 float4, 8/thread, lane-contiguous LDS dest
    for (int j = 0; j < 8; j++) {
        int f4 = t + j * 256;
        int rr = row0 + (f4 >> 5);
        if (rr >= M) rr = M - 1;              // clamp (stores are guarded)
        g2l16(A + (size_t)rr * 128 + (f4 & 31) * 4, &xs[0][0] + f4 * 4);
    }
    // issue W stage 0: 512 float4, 2/thread
    for (int j = 0; j < 2; j++) {
        int f4 = t + j * 256;
        g2l16(W + (size_t)f4 * 4, &ws[0][0][0] + f4 * 4);
    }
    __syncthreads();   // vmcnt(0) drain: xs + ws[0] ready

    int tc = t & 31;   // col group (4 cols: dims 4tc..4tc+3)
    int tr = t >> 5;   // row group (8 rows)
    float4 acc[8];
    #pragma unroll
    for (int i = 0; i < 8; i++) acc[i] = make_float4(0.f, 0.f, 0.f, 0.f);

    for (int s = 0; s < 8; s++) {
        int cur = s & 1;
        if (s < 7) {   // prefetch next W stage into alternate buffer
            for (int j = 0; j < 2; j++) {
                int f4 = t + j * 256;
                g2l16(W + (size_t)(s + 1) * BK * 128 + (size_t)f4 * 4,
                      &ws[cur ^ 1][0][0] + f4 * 4);
            }
        }
        #pragma unroll 2
        for (int k4 = 0; k4 < 4; k4++) {
            int kb = k4 * 4;
            float4 w0 = *(float4*)&ws[cur][kb + 0][tc * 4];
            float4 w1 = *(float4*)&ws[cur][kb + 1][tc * 4];
            float4 w2 = *(float4*)&ws[cur][kb + 2][tc * 4];
            float4 w3 = *(float4*)&ws[cur][kb + 3][tc * 4];
            #pragma unroll
            for (int i = 0; i < 8; i++) {
                float4 xv = *(float4*)&xs[tr * 8 + i][s * BK + kb];
                acc[i].x += xv.x * w0.x + xv.y * w1.x + xv.z * w2.x + xv.w * w3.x;
                acc[i].y += xv.x * w0.y + xv.y * w1.y + xv.z * w2.y + xv.w * w3.y;
                acc[i].z += xv.x * w0.z + xv.y * w1.z + xv.z * w2.z + xv.w * w3.z;
                acc[i].w += xv.x * w0.w + xv.y * w1.w + xv.z * w2.w + xv.w * w3.w;
            }
        }
        __syncthreads();   // drains prefetch + guards buffer reuse
    }

    // epilogue: fp16 copy + el/er
    float4 alv = ((const float4*)al)[tc];
    float4 arv = ((const float4*)ar)[tc];
    #pragma unroll
    for (int i = 0; i < 8; i++) {
        int gr = row0 + tr * 8 + i;
        // fp16 store: dims 4tc..4tc+3 of row gr
        if (gr < M) {
            __half2 p0 = __floats2half2_rn(acc[i].x, acc[i].y);
            __half2 p1 = __floats2half2_rn(acc[i].z, acc[i].w);
            uint2 pk;
            pk.x = *(unsigned*)&p0;
            pk.y = *(unsigned*)&p1;
            ((uint2*)(hb + (size_t)gr * 128))[tc] = pk;
        }
        // el/er: 16-lane shfl reduce per head
        float pl = acc[i].x * alv.x + acc[i].y * alv.y + acc[i].z * alv.z + acc[i].w * alv.w;
        float pr = acc[i].x * arv.x + acc[i].y * arv.y + acc[i].z * arv.z + acc[i].w * arv.w;
        pl += __shfl_xor(pl, 1);  pr += __shfl_xor(pr, 1);
        pl += __shfl_xor(pl, 2);  pr += __shfl_xor(pr, 2);
        pl += __shfl_xor(pl, 4);  pr += __shfl_xor(pr, 4);
        pl += __shfl_xor(pl, 8);  pr += __shfl_xor(pr, 8);
        if ((tc & 15) == 0 && gr < M) {
            int hd = tc >> 4;
            el[gr * 2 + hd] = pl;
            er[gr * 2 + hd] = pr;
        }
    }
}

// ---------------- aggregate ----------------
// One wave per node. Fast path (deg<64): lane i holds edge i's (src, alpha);
// accumulate does 4 edges/iter: lane quarter q handles edge 4kk+q, 8 dims/lane
// (16B fp16 load), then 2-step cross-quarter shfl combine.

template <bool RELU>
__global__ __launch_bounds__(256) void k_agg(const __half* __restrict__ hb,
                                             const float* __restrict__ el,
                                             const float* __restrict__ er,
                                             const int* __restrict__ rowStart,
                                             const int* __restrict__ csr,
                                             const float* __restrict__ bias,
                                             float* __restrict__ out, int N) {
    int wave = threadIdx.x >> 6;
    int lane = threadIdx.x & 63;
    int n = blockIdx.x * 4 + wave;
    if (n >= N) return;

    int rs = rowStart[n];
    int deg = rowStart[n + 1] - rs;   // in-edges; self-loop at index deg
    float2 erv = ((const float2*)er)[n];

    if (deg < 64) {
        int sreg = n;
        float e0reg = -3e38f, e1reg = -3e38f;
        if (lane <= deg) {
            sreg = (lane == deg) ? n : csr[rs + lane];
            float2 ev = ((const float2*)el)[sreg];
            float e0 = ev.x + erv.x;
            e0reg = (e0 >= 0.f) ? e0 : NEG_SLOPE * e0;
            float e1 = ev.y + erv.y;
            e1reg = (e1 >= 0.f) ? e1 : NEG_SLOPE * e1;
        }
        float m0 = e0reg, m1 = e1reg;
        for (int off = 32; off > 0; off >>= 1) {
            m0 = fmaxf(m0, __shfl_xor(m0, off));
            m1 = fmaxf(m1, __shfl_xor(m1, off));
        }
        float ex0 = 0.f, ex1 = 0.f;
        if (lane <= deg) {
            ex0 = __expf(e0reg - m0);
            ex1 = __expf(e1reg - m1);
        }
        float s0 = ex0, s1 = ex1;
        for (int off = 32; off > 0; off >>= 1) {
            s0 += __shfl_xor(s0, off);
            s1 += __shfl_xor(s1, off);
        }
        float alpha0 = ex0 * (1.0f / s0);   // 0 for lanes > deg
        float alpha1 = ex1 * (1.0f / s1);

        int q = lane >> 4;      // edge sub-slot 0..3
        int c = lane & 15;      // dim block: dims 8c..8c+7; head = c>=8
        float acc0 = 0.f, acc1 = 0.f, acc2 = 0.f, acc3 = 0.f;
        float acc4 = 0.f, acc5 = 0.f, acc6 = 0.f, acc7 = 0.f;
        int cnt = deg + 1;
        int iters = (cnt + 3) >> 2;   // <=16, so j<=63 always (no shfl wrap)
        #pragma unroll 2
        for (int kk = 0; kk < iters; ++kk) {
            int j = 4 * kk + q;        // j>deg lanes: alpha=0, sreg=n (safe)
            float a0b = __shfl(alpha0, j);
            float a1b = __shfl(alpha1, j);
            int   sj  = __shfl(sreg, j);
            float a = (c >= 8) ? a1b : a0b;
            uint4 hv = ((const uint4*)(hb + (size_t)sj * 128))[c];
            __half2 h0 = *(__half2*)&hv.x;
            __half2 h1 = *(__half2*)&hv.y;
            __half2 h2 = *(__half2*)&hv.z;
            __half2 h3 = *(__half2*)&hv.w;
            float2 f0 = __half22float2(h0);
            float2 f1 = __half22float2(h1);
            float2 f2 = __half22float2(h2);
            float2 f3 = __half22float2(h3);
            acc0 += a * f0.x;  acc1 += a * f0.y;
            acc2 += a * f1.x;  acc3 += a * f1.y;
            acc4 += a * f2.x;  acc5 += a * f2.y;
            acc6 += a * f3.x;  acc7 += a * f3.y;
        }
        // combine the 4 quarters (lanes c, c+16, c+32, c+48)
        acc0 += __shfl_xor(acc0, 16); acc1 += __shfl_xor(acc1, 16);
        acc2 += __shfl_xor(acc2, 16); acc3 += __shfl_xor(acc3, 16);
        acc4 += __shfl_xor(acc4, 16); acc5 += __shfl_xor(acc5, 16);
        acc6 += __shfl_xor(acc6, 16); acc7 += __shfl_xor(acc7, 16);
        acc0 += __shfl_xor(acc0, 32); acc1 += __shfl_xor(acc1, 32);
        acc2 += __shfl_xor(acc2, 32); acc3 += __shfl_xor(acc3, 32);
        acc4 += __shfl_xor(acc4, 32); acc5 += __shfl_xor(acc5, 32);
        acc6 += __shfl_xor(acc6, 32); acc7 += __shfl_xor(acc7, 32);
        if (lane < 16) {
            const float4* bp = (const float4*)(bias + c * 8);
            float4 b0 = bp[0], b1 = bp[1];
            float4 o0 = make_float4(acc0 + b0.x, acc1 + b0.y, acc2 + b0.z, acc3 + b0.w);
            float4 o1 = make_float4(acc4 + b1.x, acc5 + b1.y, acc6 + b1.z, acc7 + b1.w);
            if (RELU) {
                o0.x = fmaxf(o0.x, 0.f); o0.y = fmaxf(o0.y, 0.f);
                o0.z = fmaxf(o0.z, 0.f); o0.w = fmaxf(o0.w, 0.f);
                o1.x = fmaxf(o1.x, 0.f); o1.y = fmaxf(o1.y, 0.f);
                o1.z = fmaxf(o1.z, 0.f); o1.w = fmaxf(o1.w, 0.f);
            }
            float4* op = (float4*)(out + (size_t)n * 128 + c * 8);
            op[0] = o0;
            op[1] = o1;
        }
    } else {
        // ---- general path (deg >= 64): strided passes, 2 dims/lane fp16 ----
        float m0 = -3e38f, m1 = -3e38f;
        for (int i = lane; i <= deg; i += 64) {
            int s = (i == deg) ? n : csr[rs + i];
            float2 ev = ((const float2*)el)[s];
            float e0 = ev.x + erv.x;
            e0 = (e0 >= 0.f) ? e0 : NEG_SLOPE * e0;
            float e1 = ev.y + erv.y;
            e1 = (e1 >= 0.f) ? e1 : NEG_SLOPE * e1;
            m0 = fmaxf(m0, e0);
            m1 = fmaxf(m1, e1);
        }
        for (int off = 32; off > 0; off >>= 1) {
            m0 = fmaxf(m0, __shfl_xor(m0, off));
            m1 = fmaxf(m1, __shfl_xor(m1, off));
        }
        float s0 = 0.f, s1 = 0.f;
        for (int i = lane; i <= deg; i += 64) {
            int s = (i == deg) ? n : csr[rs + i];
            float2 ev = ((const float2*)el)[s];
            float e0 = ev.x + erv.x;
            e0 = (e0 >= 0.f) ? e0 : NEG_SLOPE * e0;
            float e1 = ev.y + erv.y;
            e1 = (e1 >= 0.f) ? e1 : NEG_SLOPE * e1;
            s0 += __expf(e0 - m0);
            s1 += __expf(e1 - m1);
        }
        for (int off = 32; off > 0; off >>= 1) {
            s0 += __shfl_xor(s0, off);
            s1 += __shfl_xor(s1, off);
        }
        float inv0 = 1.0f / s0, inv1 = 1.0f / s1;
        float mh = (lane < 32) ? m0 : m1;
        float invh = (lane < 32) ? inv0 : inv1;
        float erh = (lane < 32) ? erv.x : erv.y;
        float a0 = 0.f, a1 = 0.f;
        for (int j = 0; j <= deg; j++) {
            int sj = (j == deg) ? n : csr[rs + j];
            float elh = el[sj * 2 + (lane >> 5)];
            float e = elh + erh;
            e = (e >= 0.f) ? e : NEG_SLOPE * e;
            float alpha = __expf(e - mh) * invh;
            unsigned hv = ((const unsigned*)(hb + (size_t)sj * 128))[lane];
            float2 f = __half22float2(*(__half2*)&hv);
            a0 += alpha * f.x;
            a1 += alpha * f.y;
        }
        float2 bv = ((const float2*)bias)[lane];
        a0 += bv.x;
        a1 += bv.y;
        if (RELU) {
            a0 = fmaxf(a0, 0.f);
            a1 = fmaxf(a1, 0.f);
        }
        ((float2*)(out + (size_t)n * 128))[lane] = make_float2(a0, a1);
    }
}

// ---------------- launcher ----------------

static inline size_t align_up(size_t v, size_t a) { return (v + a - 1) & ~(a - 1); }

extern "C" void kernel_launch(void* const* d_in, const int* in_sizes, int n_in,
                              void* d_out, int out_size, void* d_ws, size_t ws_size,
                              hipStream_t stream) {
    const float* x   = (const float*)d_in[0];
    const int*   src = (const int*)d_in[1];
    const int*   dst = (const int*)d_in[2];
    const float* W1  = (const float*)d_in[3];
    const float* al1 = (const float*)d_in[4];
    const float* ar1 = (const float*)d_in[5];
    const float* b1  = (const float*)d_in[6];
    const float* W2  = (const float*)d_in[7];
    const float* al2 = (const float*)d_in[8];
    const float* ar2 = (const float*)d_in[9];
    const float* b2  = (const float*)d_in[10];
    float* out = (float*)d_out;

    const int N = in_sizes[0] / 128;
    const int E = in_sizes[1];
    const int NB = (N + SCAN_CHUNK - 1) / SCAN_CHUNK;

    char* ws = (char*)d_ws;
    size_t off = 0;
    float*  bufB = (float*)(ws + off);  off = align_up(off + (size_t)N * 128 * 4, 256);
    __half* hb   = (__half*)(ws + off); off = align_up(off + (size_t)N * 128 * 2, 256);
    float* el   = (float*)(ws + off); off = align_up(off + (size_t)N * 2 * 4, 256);
    float* er   = (float*)(ws + off); off = align_up(off + (size_t)N * 2 * 4, 256);
    int* rowStart = (int*)(ws + off); off = align_up(off + (size_t)(N + 1) * 4, 256);
    int* cursor   = (int*)(ws + off); off = align_up(off + (size_t)N * 4, 256);
    int* deg      = (int*)(ws + off); off = align_up(off + (size_t)N * 4, 256);
    int* bsum     = (int*)(ws + off); off = align_up(off + 256 * 4, 256);
    int* csr      = (int*)(ws + off); off = align_up(off + (size_t)E * 4, 256);

    hipMemsetAsync(deg, 0, (size_t)N * 4, stream);
    k_hist<<<(E + 255) / 256, 256, 0, stream>>>(dst, E, deg);
    k_block_sum<<<NB, 256, 0, stream>>>(deg, N, bsum);
    k_scan_bsum<<<1, 256, 0, stream>>>(bsum, NB);
    k_scan_final<<<NB, 256, 0, stream>>>(deg, N, bsum, rowStart, cursor, E);
    k_scatter<<<(E + 255) / 256, 256, 0, stream>>>(src, dst, E, cursor, csr);

    const int gemm_grid = (N + 63) / 64;
    const int agg_grid = (N + 3) / 4;

    k_gemm_fused<<<gemm_grid, 256, 0, stream>>>(x, W1, hb, al1, ar1, el, er, N);
    k_agg<true><<<agg_grid, 256, 0, stream>>>(hb, el, er, rowStart, csr, b1, bufB, N);

    k_gemm_fused<<<gemm_grid, 256, 0, stream>>>(bufB, W2, hb, al2, ar2, el, er, N);
    k_agg<false><<<agg_grid, 256, 0, stream>>>(hb, el, er, rowStart, csr, b2, out, N);
}

// Round 5
// 346.543 us; speedup vs baseline: 10.5870x; 1.4065x over previous
//
#include <hip/hip_runtime.h>
#include <hip/hip_fp16.h>

// 2-layer GAT, H=2 heads, D=64 per head, F_IN=128.
// Bucketed CSR build (by dst) -> [GEMM(fp32, fused el/er + fp16 h-copy) -> aggregate] x2.
// CSR build: bucket = dst>>8 (256 nodes/bucket). Bucket counts (LDS-aggregated)
// -> 1-block scan -> bucket-local edge placement (packed src|dstLow, 4B) ->
// per-bucket block builds rowStart + csr entirely within a ~16KB L2-dense window.
// Assumes N <= 131072 (src packs in 17 bits) and NBUCK <= 512 -- true for N=100K.

#define NEG_SLOPE 0.2f
#define BSHIFT 8
#define ETILE 4096

// ---------------- CSR build (bucketed) ----------------

__global__ __launch_bounds__(256) void k_bcount(const int* __restrict__ dst, int E,
                                                int nbuck, int* __restrict__ bcnt) {
    __shared__ int cnt[512];
    int t = threadIdx.x;
    for (int b = t; b < nbuck; b += 256) cnt[b] = 0;
    __syncthreads();
    int e0 = blockIdx.x * ETILE;
    #pragma unroll
    for (int j = 0; j < ETILE / 256; j++) {
        int e = e0 + j * 256 + t;
        if (e < E) atomicAdd(&cnt[dst[e] >> BSHIFT], 1);
    }
    __syncthreads();
    for (int b = t; b < nbuck; b += 256) {
        int c = cnt[b];
        if (c > 0) atomicAdd(&bcnt[b], c);
    }
}

__global__ __launch_bounds__(256) void k_bscan(const int* __restrict__ bcnt, int nbuck,
                                               int* __restrict__ bbase,
                                               int* __restrict__ bcursor,
                                               int* __restrict__ rowStart, int N, int E) {
    __shared__ int sa[512], sb[512];
    int t = threadIdx.x;
    sa[t] = (t < nbuck) ? bcnt[t] : 0;
    sa[t + 256] = (t + 256 < nbuck) ? bcnt[t + 256] : 0;
    __syncthreads();
    int* a = sa;
    int* b = sb;
    for (int off = 1; off < 512; off <<= 1) {
        b[t] = a[t] + ((t >= off) ? a[t - off] : 0);
        int i = t + 256;
        b[i] = a[i] + ((i >= off) ? a[i - off] : 0);
        __syncthreads();
        int* tmp = a; a = b; b = tmp;
    }
    // a = inclusive scan of bucket counts
    #pragma unroll
    for (int k = 0; k < 2; k++) {
        int i = t + k * 256;
        if (i <= nbuck) {
            int e_ = (i == 0) ? 0 : a[i - 1];
            bbase[i] = e_;
            if (i < nbuck) bcursor[i] = e_;
        }
    }
    if (t == 0) rowStart[N] = E;
}

__global__ __launch_bounds__(256) void k_bucket(const int* __restrict__ src,
                                                const int* __restrict__ dst, int E,
                                                int nbuck, int* __restrict__ bcursor,
                                                int* __restrict__ ebuf) {
    __shared__ int cnt[512];
    __shared__ int base[512];
    int t = threadIdx.x;
    for (int b = t; b < nbuck; b += 256) cnt[b] = 0;
    __syncthreads();
    int e0 = blockIdx.x * ETILE;
    int dv[ETILE / 256], sv[ETILE / 256];
    #pragma unroll
    for (int j = 0; j < ETILE / 256; j++) {
        int e = e0 + j * 256 + t;
        dv[j] = -1;
        if (e < E) {
            dv[j] = dst[e];
            sv[j] = src[e];
            atomicAdd(&cnt[dv[j] >> BSHIFT], 1);
        }
    }
    __syncthreads();
    for (int b = t; b < nbuck; b += 256) {
        int c = cnt[b];
        base[b] = (c > 0) ? atomicAdd(&bcursor[b], c) : 0;
    }
    __syncthreads();
    for (int b = t; b < nbuck; b += 256) cnt[b] = 0;
    __syncthreads();
    #pragma unroll
    for (int j = 0; j < ETILE / 256; j++) {
        if (dv[j] >= 0) {
            int bk = dv[j] >> BSHIFT;
            int r = atomicAdd(&cnt[bk], 1);
            ebuf[base[bk] + r] = sv[j] | ((dv[j] & ((1 << BSHIFT) - 1)) << 17);
        }
    }
}

__global__ __launch_bounds__(256) void k_build(const int* __restrict__ ebuf,
                                               const int* __restrict__ bbase,
                                               int* __restrict__ rowStart,
                                               int* __restrict__ csr, int N) {
    __shared__ int dcnt[256];
    __shared__ int sa[256], sb[256];
    __shared__ int cur[256];
    int b = blockIdx.x;
    int t = threadIdx.x;
    int lo = bbase[b], hi = bbase[b + 1];
    int n0 = b << BSHIFT;
    dcnt[t] = 0;
    __syncthreads();
    for (int p = lo + t; p < hi; p += 256)
        atomicAdd(&dcnt[((unsigned)ebuf[p]) >> 17], 1);
    __syncthreads();
    sa[t] = dcnt[t];
    __syncthreads();
    int* a = sa;
    int* bq = sb;
    for (int off = 1; off < 256; off <<= 1) {
        bq[t] = a[t] + ((t >= off) ? a[t - off] : 0);
        __syncthreads();
        int* tmp = a; a = bq; bq = tmp;
    }
    int excl = (t == 0) ? 0 : a[t - 1];
    int pos0 = lo + excl;
    if (n0 + t < N) rowStart[n0 + t] = pos0;
    cur[t] = pos0;
    __syncthreads();
    for (int p = lo + t; p < hi; p += 256) {
        int v = ebuf[p];
        int pos = atomicAdd(&cur[((unsigned)v) >> 17], 1);
        csr[pos] = v & 0x1FFFF;
    }
}

// ---------------- fused GEMM ----------------
// h = A[M,128] @ W[128,128]; outputs: hb (fp16 copy of h, for gathers),
// el/er [M,2] attention projections. fp32 C is never materialized.
// W staged via global_load_lds into double-buffered LDS (BK=16), 1 barrier/stage.

__device__ __forceinline__ void g2l16(const float* g, void* l) {
    __builtin_amdgcn_global_load_lds((const __attribute__((address_space(1))) void*)g,
                                     (__attribute__((address_space(3))) void*)l, 16, 0, 0);
}

#define BK 16
__global__ __launch_bounds__(256, 4) void k_gemm_fused(const float* __restrict__ A,
                                                       const float* __restrict__ W,
                                                       __half* __restrict__ hb,
                                                       const float* __restrict__ al,
                                                       const float* __restrict__ ar,
                                                       float* __restrict__ el,
                                                       float* __restrict__ er, int M) {
    __shared__ float xs[64][128];        // 32 KB
    __shared__ float ws[2][BK][128];     // 16 KB (double-buffered)
    int row0 = blockIdx.x * 64;
    int t = threadIdx.x;

    for (int j = 0; j < 8; j++) {
        int f4 = t + j * 256;
        int rr = row0 + (f4 >> 5);
        if (rr >= M) rr = M - 1;              // clamp (stores are guarded)
        g2l16(A + (size_t)rr * 128 + (f4 & 31) * 4, &xs[0][0] + f4 * 4);
    }
    for (int j = 0; j < 2; j++) {
        int f4 = t + j * 256;
        g2l16(W + (size_t)f4 * 4, &ws[0][0][0] + f4 * 4);
    }
    __syncthreads();

    int tc = t & 31;
    int tr = t >> 5;
    float4 acc[8];
    #pragma unroll
    for (int i = 0; i < 8; i++) acc[i] = make_float4(0.f, 0.f, 0.f, 0.f);

    for (int s = 0; s < 8; s++) {
        int cur = s & 1;
        if (s < 7) {
            for (int j = 0; j < 2; j++) {
                int f4 = t + j * 256;
                g2l16(W + (size_t)(s + 1) * BK * 128 + (size_t)f4 * 4,
                      &ws[cur ^ 1][0][0] + f4 * 4);
            }
        }
        #pragma unroll 2
        for (int k4 = 0; k4 < 4; k4++) {
            int kb = k4 * 4;
            float4 w0 = *(float4*)&ws[cur][kb + 0][tc * 4];
            float4 w1 = *(float4*)&ws[cur][kb + 1][tc * 4];
            float4 w2 = *(float4*)&ws[cur][kb + 2][tc * 4];
            float4 w3 = *(float4*)&ws[cur][kb + 3][tc * 4];
            #pragma unroll
            for (int i = 0; i < 8; i++) {
                float4 xv = *(float4*)&xs[tr * 8 + i][s * BK + kb];
                acc[i].x += xv.x * w0.x + xv.y * w1.x + xv.z * w2.x + xv.w * w3.x;
                acc[i].y += xv.x * w0.y + xv.y * w1.y + xv.z * w2.y + xv.w * w3.y;
                acc[i].z += xv.x * w0.z + xv.y * w1.z + xv.z * w2.z + xv.w * w3.z;
                acc[i].w += xv.x * w0.w + xv.y * w1.w + xv.z * w2.w + xv.w * w3.w;
            }
        }
        __syncthreads();
    }

    float4 alv = ((const float4*)al)[tc];
    float4 arv = ((const float4*)ar)[tc];
    #pragma unroll
    for (int i = 0; i < 8; i++) {
        int gr = row0 + tr * 8 + i;
        if (gr < M) {
            __half2 p0 = __floats2half2_rn(acc[i].x, acc[i].y);
            __half2 p1 = __floats2half2_rn(acc[i].z, acc[i].w);
            uint2 pk;
            pk.x = *(unsigned*)&p0;
            pk.y = *(unsigned*)&p1;
            ((uint2*)(hb + (size_t)gr * 128))[tc] = pk;
        }
        float pl = acc[i].x * alv.x + acc[i].y * alv.y + acc[i].z * alv.z + acc[i].w * alv.w;
        float pr = acc[i].x * arv.x + acc[i].y * arv.y + acc[i].z * arv.z + acc[i].w * arv.w;
        pl += __shfl_xor(pl, 1);  pr += __shfl_xor(pr, 1);
        pl += __shfl_xor(pl, 2);  pr += __shfl_xor(pr, 2);
        pl += __shfl_xor(pl, 4);  pr += __shfl_xor(pr, 4);
        pl += __shfl_xor(pl, 8);  pr += __shfl_xor(pr, 8);
        if ((tc & 15) == 0 && gr < M) {
            int hd = tc >> 4;
            el[gr * 2 + hd] = pl;
            er[gr * 2 + hd] = pr;
        }
    }
}

// ---------------- aggregate ----------------
// One wave per node. Fast path (deg<64): lane i holds edge i's (src, alpha);
// accumulate does 4 edges/iter: lane quarter q handles edge 4kk+q, 8 dims/lane
// (16B fp16 load), then 2-step cross-quarter shfl combine.

template <bool RELU>
__global__ __launch_bounds__(256) void k_agg(const __half* __restrict__ hb,
                                             const float* __restrict__ el,
                                             const float* __restrict__ er,
                                             const int* __restrict__ rowStart,
                                             const int* __restrict__ csr,
                                             const float* __restrict__ bias,
                                             float* __restrict__ out, int N) {
    int wave = threadIdx.x >> 6;
    int lane = threadIdx.x & 63;
    int n = blockIdx.x * 4 + wave;
    if (n >= N) return;

    int rs = rowStart[n];
    int deg = rowStart[n + 1] - rs;
    float2 erv = ((const float2*)er)[n];

    if (deg < 64) {
        int sreg = n;
        float e0reg = -3e38f, e1reg = -3e38f;
        if (lane <= deg) {
            sreg = (lane == deg) ? n : csr[rs + lane];
            float2 ev = ((const float2*)el)[sreg];
            float e0 = ev.x + erv.x;
            e0reg = (e0 >= 0.f) ? e0 : NEG_SLOPE * e0;
            float e1 = ev.y + erv.y;
            e1reg = (e1 >= 0.f) ? e1 : NEG_SLOPE * e1;
        }
        float m0 = e0reg, m1 = e1reg;
        for (int off = 32; off > 0; off >>= 1) {
            m0 = fmaxf(m0, __shfl_xor(m0, off));
            m1 = fmaxf(m1, __shfl_xor(m1, off));
        }
        float ex0 = 0.f, ex1 = 0.f;
        if (lane <= deg) {
            ex0 = __expf(e0reg - m0);
            ex1 = __expf(e1reg - m1);
        }
        float s0 = ex0, s1 = ex1;
        for (int off = 32; off > 0; off >>= 1) {
            s0 += __shfl_xor(s0, off);
            s1 += __shfl_xor(s1, off);
        }
        float alpha0 = ex0 * (1.0f / s0);
        float alpha1 = ex1 * (1.0f / s1);

        int q = lane >> 4;
        int c = lane & 15;
        float acc0 = 0.f, acc1 = 0.f, acc2 = 0.f, acc3 = 0.f;
        float acc4 = 0.f, acc5 = 0.f, acc6 = 0.f, acc7 = 0.f;
        int cnt = deg + 1;
        int iters = (cnt + 3) >> 2;
        #pragma unroll 2
        for (int kk = 0; kk < iters; ++kk) {
            int j = 4 * kk + q;
            float a0b = __shfl(alpha0, j);
            float a1b = __shfl(alpha1, j);
            int   sj  = __shfl(sreg, j);
            float a = (c >= 8) ? a1b : a0b;
            uint4 hv = ((const uint4*)(hb + (size_t)sj * 128))[c];
            float2 f0 = __half22float2(*(__half2*)&hv.x);
            float2 f1 = __half22float2(*(__half2*)&hv.y);
            float2 f2 = __half22float2(*(__half2*)&hv.z);
            float2 f3 = __half22float2(*(__half2*)&hv.w);
            acc0 += a * f0.x;  acc1 += a * f0.y;
            acc2 += a * f1.x;  acc3 += a * f1.y;
            acc4 += a * f2.x;  acc5 += a * f2.y;
            acc6 += a * f3.x;  acc7 += a * f3.y;
        }
        acc0 += __shfl_xor(acc0, 16); acc1 += __shfl_xor(acc1, 16);
        acc2 += __shfl_xor(acc2, 16); acc3 += __shfl_xor(acc3, 16);
        acc4 += __shfl_xor(acc4, 16); acc5 += __shfl_xor(acc5, 16);
        acc6 += __shfl_xor(acc6, 16); acc7 += __shfl_xor(acc7, 16);
        acc0 += __shfl_xor(acc0, 32); acc1 += __shfl_xor(acc1, 32);
        acc2 += __shfl_xor(acc2, 32); acc3 += __shfl_xor(acc3, 32);
        acc4 += __shfl_xor(acc4, 32); acc5 += __shfl_xor(acc5, 32);
        acc6 += __shfl_xor(acc6, 32); acc7 += __shfl_xor(acc7, 32);
        if (lane < 16) {
            const float4* bp = (const float4*)(bias + c * 8);
            float4 b0 = bp[0], b1 = bp[1];
            float4 o0 = make_float4(acc0 + b0.x, acc1 + b0.y, acc2 + b0.z, acc3 + b0.w);
            float4 o1 = make_float4(acc4 + b1.x, acc5 + b1.y, acc6 + b1.z, acc7 + b1.w);
            if (RELU) {
                o0.x = fmaxf(o0.x, 0.f); o0.y = fmaxf(o0.y, 0.f);
                o0.z = fmaxf(o0.z, 0.f); o0.w = fmaxf(o0.w, 0.f);
                o1.x = fmaxf(o1.x, 0.f); o1.y = fmaxf(o1.y, 0.f);
                o1.z = fmaxf(o1.z, 0.f); o1.w = fmaxf(o1.w, 0.f);
            }
            float4* op = (float4*)(out + (size_t)n * 128 + c * 8);
            op[0] = o0;
            op[1] = o1;
        }
    } else {
        float m0 = -3e38f, m1 = -3e38f;
        for (int i = lane; i <= deg; i += 64) {
            int s = (i == deg) ? n : csr[rs + i];
            float2 ev = ((const float2*)el)[s];
            float e0 = ev.x + erv.x;
            e0 = (e0 >= 0.f) ? e0 : NEG_SLOPE * e0;
            float e1 = ev.y + erv.y;
            e1 = (e1 >= 0.f) ? e1 : NEG_SLOPE * e1;
            m0 = fmaxf(m0, e0);
            m1 = fmaxf(m1, e1);
        }
        for (int off = 32; off > 0; off >>= 1) {
            m0 = fmaxf(m0, __shfl_xor(m0, off));
            m1 = fmaxf(m1, __shfl_xor(m1, off));
        }
        float s0 = 0.f, s1 = 0.f;
        for (int i = lane; i <= deg; i += 64) {
            int s = (i == deg) ? n : csr[rs + i];
            float2 ev = ((const float2*)el)[s];
            float e0 = ev.x + erv.x;
            e0 = (e0 >= 0.f) ? e0 : NEG_SLOPE * e0;
            float e1 = ev.y + erv.y;
            e1 = (e1 >= 0.f) ? e1 : NEG_SLOPE * e1;
            s0 += __expf(e0 - m0);
            s1 += __expf(e1 - m1);
        }
        for (int off = 32; off > 0; off >>= 1) {
            s0 += __shfl_xor(s0, off);
            s1 += __shfl_xor(s1, off);
        }
        float inv0 = 1.0f / s0, inv1 = 1.0f / s1;
        float mh = (lane < 32) ? m0 : m1;
        float invh = (lane < 32) ? inv0 : inv1;
        float erh = (lane < 32) ? erv.x : erv.y;
        float a0 = 0.f, a1 = 0.f;
        for (int j = 0; j <= deg; j++) {
            int sj = (j == deg) ? n : csr[rs + j];
            float elh = el[sj * 2 + (lane >> 5)];
            float e = elh + erh;
            e = (e >= 0.f) ? e : NEG_SLOPE * e;
            float alpha = __expf(e - mh) * invh;
            unsigned hv = ((const unsigned*)(hb + (size_t)sj * 128))[lane];
            float2 f = __half22float2(*(__half2*)&hv);
            a0 += alpha * f.x;
            a1 += alpha * f.y;
        }
        float2 bv = ((const float2*)bias)[lane];
        a0 += bv.x;
        a1 += bv.y;
        if (RELU) {
            a0 = fmaxf(a0, 0.f);
            a1 = fmaxf(a1, 0.f);
        }
        ((float2*)(out + (size_t)n * 128))[lane] = make_float2(a0, a1);
    }
}

// ---------------- launcher ----------------

static inline size_t align_up(size_t v, size_t a) { return (v + a - 1) & ~(a - 1); }

extern "C" void kernel_launch(void* const* d_in, const int* in_sizes, int n_in,
                              void* d_out, int out_size, void* d_ws, size_t ws_size,
                              hipStream_t stream) {
    const float* x   = (const float*)d_in[0];
    const int*   src = (const int*)d_in[1];
    const int*   dst = (const int*)d_in[2];
    const float* W1  = (const float*)d_in[3];
    const float* al1 = (const float*)d_in[4];
    const float* ar1 = (const float*)d_in[5];
    const float* b1  = (const float*)d_in[6];
    const float* W2  = (const float*)d_in[7];
    const float* al2 = (const float*)d_in[8];
    const float* ar2 = (const float*)d_in[9];
    const float* b2  = (const float*)d_in[10];
    float* out = (float*)d_out;

    const int N = in_sizes[0] / 128;
    const int E = in_sizes[1];
    const int NBUCK = (N + 255) >> 8;

    char* ws = (char*)d_ws;
    size_t off = 0;
    float*  bufB = (float*)(ws + off);  off = align_up(off + (size_t)N * 128 * 4, 256);
    __half* hb   = (__half*)(ws + off); off = align_up(off + (size_t)N * 128 * 2, 256);
    float* el   = (float*)(ws + off); off = align_up(off + (size_t)N * 2 * 4, 256);
    float* er   = (float*)(ws + off); off = align_up(off + (size_t)N * 2 * 4, 256);
    int* rowStart = (int*)(ws + off); off = align_up(off + (size_t)(N + 1) * 4, 256);
    int* csr      = (int*)(ws + off); off = align_up(off + (size_t)E * 4, 256);
    int* ebuf     = (int*)(ws + off); off = align_up(off + (size_t)E * 4, 256);
    int* bcnt     = (int*)(ws + off); off = align_up(off + (size_t)NBUCK * 4, 256);
    int* bbase    = (int*)(ws + off); off = align_up(off + (size_t)(NBUCK + 1) * 4, 256);
    int* bcursor  = (int*)(ws + off); off = align_up(off + (size_t)NBUCK * 4, 256);

    const int etile_grid = (E + ETILE - 1) / ETILE;

    hipMemsetAsync(bcnt, 0, (size_t)NBUCK * 4, stream);
    k_bcount<<<etile_grid, 256, 0, stream>>>(dst, E, NBUCK, bcnt);
    k_bscan<<<1, 256, 0, stream>>>(bcnt, NBUCK, bbase, bcursor, rowStart, N, E);
    k_bucket<<<etile_grid, 256, 0, stream>>>(src, dst, E, NBUCK, bcursor, ebuf);
    k_build<<<NBUCK, 256, 0, stream>>>(ebuf, bbase, rowStart, csr, N);

    const int gemm_grid = (N + 63) / 64;
    const int agg_grid = (N + 3) / 4;

    k_gemm_fused<<<gemm_grid, 256, 0, stream>>>(x, W1, hb, al1, ar1, el, er, N);
    k_agg<true><<<agg_grid, 256, 0, stream>>>(hb, el, er, rowStart, csr, b1, bufB, N);

    k_gemm_fused<<<gemm_grid, 256, 0, stream>>>(bufB, W2, hb, al2, ar2, el, er, N);
    k_agg<false><<<agg_grid, 256, 0, stream>>>(hb, el, er, rowStart, csr, b2, out, N);
}